// Round 10
// baseline (820.945 us; speedup 1.0000x reference)
//
#include <hip/hip_runtime.h>

#define NB   512
#define NN   50
#define LLn  50
#define HD   128
#define OUTN 99999

// ---------------- ws byte offsets ----------------
#define WS_W1T   0         // fp32 [128][128] transposed
#define WS_W2T   65536     // fp32 [128][128] transposed
#define WS_WTT   131072    // fp32 [256][128] transposed
#define WS_WEH   262144    // bf16 hi [256 n][128 k]  (rows 0-127 W_ein, 128-255 W_eout)
#define WS_WEL   327680    // bf16 lo
#define WS_WCATH 393216    // bf16 hi [384 n][384 k]  (k<256 w_ih, k>=256 w_hh)
#define WS_WCATL 688128    // bf16 lo
#define WS_AHI   983040    // a-final hi image [2 kh][512 b][128 B]
#define WS_ALO   1114112

// ---------------- k1f LDS layout (bytes), alloc 81920 -> 2 blocks/CU ----------------
// 0      HH    [50][256B] bf16 hi swizzled (MFMA rows 50-63 overrun into HL: discarded)
// 12800  HL    [50][256B] bf16 lo          (overrun into IMG0H: discarded)
// 25600  IMG0H [50][256B] bf16 hi (IN kh0) | later H2f [50][128]f plain
// 38400  IMG0L [50][256B]
// 51200  HEf   [50][128]f swizzled (he column-half)
//        -> after a_mul(1): IMG1H@51200, IMG1L@64000 (overrun to 80368 < 81920: ok)
//        -> in P5: SIG [50][128]f plain @51200
// P5 small buffers overlay HH: Q1P@0(512f) AP@2048 RP@4096 ALP@6144 ALI@6400

typedef __attribute__((ext_vector_type(8))) short bf16x8;
typedef __attribute__((ext_vector_type(4))) float f32x4;

__device__ __forceinline__ unsigned short f2bf(float f) {
  unsigned int u = __float_as_uint(f);
  unsigned int r = (u + 0x7FFFu + ((u >> 16) & 1u)) >> 16;
  return (unsigned short)r;
}
__device__ __forceinline__ float bf2f(unsigned short h) {
  return __uint_as_float(((unsigned int)h) << 16);
}
__device__ __forceinline__ void cvt4(float4 v, ushort4& hi, ushort4& lo) {
  unsigned short h0 = f2bf(v.x), h1 = f2bf(v.y), h2 = f2bf(v.z), h3 = f2bf(v.w);
  hi = make_ushort4(h0, h1, h2, h3);
  lo = make_ushort4(f2bf(v.x - bf2f(h0)), f2bf(v.y - bf2f(h1)),
                    f2bf(v.z - bf2f(h2)), f2bf(v.w - bf2f(h3)));
}
__device__ __forceinline__ void gl_lds16(const void* g, void* l) {
  __builtin_amdgcn_global_load_lds(
      (const __attribute__((address_space(1))) void*)g,
      (__attribute__((address_space(3))) void*)l, 16, 0, 0);
}
__device__ __forceinline__ float sigm(float x) { return 1.f/(1.f + __expf(-x)); }

// ================= k0: weight prep (unchanged) =================
__global__ void k0_prep(const float* __restrict__ w_ih, const float* __restrict__ w_hh,
                        const float* __restrict__ W_ein, const float* __restrict__ W_eout,
                        const float* __restrict__ W1, const float* __restrict__ W2,
                        const float* __restrict__ Wt, char* __restrict__ wsb)
{
  float* wsf = (float*)wsb;
  for (int i = blockIdx.x * blockDim.x + threadIdx.x; i < 245760; i += gridDim.x * blockDim.x) {
    int idx = i;
    if (idx < 16384) { int k = idx >> 7, c = idx & 127; wsf[idx] = W1[c*128 + k]; continue; }
    idx -= 16384;
    if (idx < 16384) { int k = idx >> 7, c = idx & 127; wsf[16384 + idx] = W2[c*128 + k]; continue; }
    idx -= 16384;
    if (idx < 32768) { int k = idx >> 7, c = idx & 127; wsf[32768 + idx] = Wt[c*256 + k]; continue; }
    idx -= 32768;
    if (idx < 32768) {
      int n = idx >> 7, k = idx & 127;
      float v = (n < 128) ? W_ein[n*128 + k] : W_eout[(n-128)*128 + k];
      unsigned short h = f2bf(v);
      *(unsigned short*)(wsb + WS_WEH + idx*2) = h;
      *(unsigned short*)(wsb + WS_WEL + idx*2) = f2bf(v - bf2f(h));
      continue;
    }
    idx -= 32768;
    {
      int n = idx / 384, k = idx % 384;
      float v = (k < 256) ? w_ih[n*256 + k] : w_hh[n*128 + (k - 256)];
      unsigned short h = f2bf(v);
      *(unsigned short*)(wsb + WS_WCATH + idx*2) = h;
      *(unsigned short*)(wsb + WS_WCATL + idx*2) = f2bf(v - bf2f(h));
    }
  }
}

// ================= k1f: fused per-sample GNN+GRU+attention =================
__global__ __launch_bounds__(512, 4) void k1f(const int* __restrict__ items,
    const float* __restrict__ A, const float* __restrict__ emb,
    const int* __restrict__ alias_in,
    const float* __restrict__ b_ein, const float* __restrict__ b_eout,
    const float* __restrict__ b_iah, const float* __restrict__ b_oah,
    const float* __restrict__ b_ih, const float* __restrict__ b_hh,
    const float* __restrict__ b1, const float* __restrict__ b2,
    const float* __restrict__ W3, const float* __restrict__ bt_,
    char* __restrict__ wsb)
{
  extern __shared__ char lds[];
  char*  HH    = lds;
  char*  HL    = lds + 12800;
  char*  IMG0H = lds + 25600;
  char*  IMG0L = lds + 38400;
  float* HEf   = (float*)(lds + 51200);
  char*  IMG1H = lds + 51200;            // overlays HEf after a_mul(1) barrier
  char*  IMG1L = lds + 64000;
  float* H2f   = (float*)(lds + 25600);  // overlays IMG0 after P4 (plain [50][128])
  float* SIG   = (float*)(lds + 51200);  // overlays HEf in P5  (plain [50][128])
  float* Q1P   = (float*)(lds + 0);      // overlays HH in P5
  float* AP    = (float*)(lds + 2048);
  float* RP    = (float*)(lds + 4096);
  float* ALP   = (float*)(lds + 6144);
  int*   ALI   = (int*)(lds + 6400);

  const int b = blockIdx.x, tid = threadIdx.x;
  const int lane = tid & 63, wid = tid >> 6, l15 = lane & 15, lq = lane >> 4;

  // ---- P1: gather embedding -> HH/HL (swizzled bf16 hi/lo, 50 rows) ----
  for (int i = tid; i < 1600; i += 512) {
    int row = i >> 5, part = i & 31;
    int it = items[b*NN + row];
    float4 v = *(const float4*)&emb[(size_t)it*128 + part*4];
    ushort4 h4v, g4v;
    cvt4(v, h4v, g4v);
    unsigned off = row*256 + (((unsigned)(part*8)) ^ (((unsigned)(row&7)) << 4));
    *(ushort4*)(HH + off) = h4v;
    *(ushort4*)(HL + off) = g4v;
  }
  __syncthreads();

  // ---- he half-GEMM: he[:, nb..nb+128) = hidden @ W_e^T (+bias) -> HEf swizzled ----
  auto he_gemm = [&](int nb, const float* __restrict__ bias) {
    f32x4 a2[4];
#pragma unroll
    for (int i = 0; i < 4; ++i) a2[i] = (f32x4){0.f,0.f,0.f,0.f};
    const int n = wid*16 + l15;
    for (int s = 0; s < 4; ++s) {
      unsigned boff = (unsigned)((nb + n)*256 + s*64 + lq*16);
      bf16x8 bh = *(const bf16x8*)(wsb + WS_WEH + boff);
      bf16x8 bl = *(const bf16x8*)(wsb + WS_WEL + boff);
#pragma unroll
      for (int i = 0; i < 4; ++i) {
        int row = i*16 + l15;
        unsigned off = row*256 + (((unsigned)(s*64 + lq*16)) ^ (((unsigned)(row&7)) << 4));
        bf16x8 ah = *(const bf16x8*)(HH + off);
        bf16x8 al = *(const bf16x8*)(HL + off);
        a2[i] = __builtin_amdgcn_mfma_f32_16x16x32_bf16(ah, bh, a2[i], 0,0,0);
        a2[i] = __builtin_amdgcn_mfma_f32_16x16x32_bf16(ah, bl, a2[i], 0,0,0);
        a2[i] = __builtin_amdgcn_mfma_f32_16x16x32_bf16(al, bh, a2[i], 0,0,0);
      }
    }
    float bv = bias[n];
#pragma unroll
    for (int i = 0; i < 4; ++i)
#pragma unroll
      for (int q = 0; q < 4; ++q) {
        int row = i*16 + lq*4 + q;
        if (row < 50) HEf[row*128 + (n ^ ((row&3)<<2))] = a2[i][q] + bv;
      }
  };

  // ---- P3: IN[:,sel-half] = A_sel @ he_half + bias -> img hi/lo (swizzled bf16) ----
  auto a_mul = [&](int sel, const float* __restrict__ biasv,
                   char* __restrict__ imgH, char* __restrict__ imgL,
                   bool barrier_before_store) {
    const int c = tid & 127, th = tid >> 7;          // th 0..3
    const int nbase = th*13;
    const int cnt = (th == 3) ? 11 : 13;
    const float* Ab = A + (size_t)b*NN*100 + sel*50;
    float acc[13];
#pragma unroll
    for (int n = 0; n < 13; ++n) acc[n] = 0.f;
    for (int m4 = 0; m4 < 48; m4 += 4) {
      float x0 = HEf[(m4+0)*128 + (c ^ (((m4+0)&3)<<2))];
      float x1 = HEf[(m4+1)*128 + (c ^ (((m4+1)&3)<<2))];
      float x2 = HEf[(m4+2)*128 + (c ^ (((m4+2)&3)<<2))];
      float x3 = HEf[(m4+3)*128 + (c ^ (((m4+3)&3)<<2))];
#pragma unroll
      for (int n = 0; n < 13; ++n) {
        if (n < cnt) {
          const float* ar = Ab + (nbase+n)*100 + m4;
          float2 a01 = *(const float2*)ar;
          float2 a23 = *(const float2*)(ar + 2);
          acc[n] += a01.x*x0 + a01.y*x1 + a23.x*x2 + a23.y*x3;
        }
      }
    }
    {
      float x0 = HEf[48*128 + c];                    // 48&3=0
      float x1 = HEf[49*128 + (c ^ 4)];              // 49&3=1
#pragma unroll
      for (int n = 0; n < 13; ++n) {
        if (n < cnt) {
          float2 a01 = *(const float2*)(Ab + (nbase+n)*100 + 48);
          acc[n] += a01.x*x0 + a01.y*x1;
        }
      }
    }
    if (barrier_before_store) __syncthreads();       // all HEf reads done
    float bv = biasv[c];
#pragma unroll
    for (int n = 0; n < 13; ++n) {
      if (n < cnt) {
        float v = acc[n] + bv;
        int row = nbase + n;
        unsigned short hi = f2bf(v);
        unsigned short lo = f2bf(v - bf2f(hi));
        unsigned byte = row*256 + (((unsigned)(c*2)) ^ (((unsigned)(row&7)) << 4));
        *(unsigned short*)(imgH + byte) = hi;
        *(unsigned short*)(imgL + byte) = lo;
      }
    }
  };

  // ---- sequential prologue: build IMG0 and IMG1 ----
  he_gemm(0, b_ein);                          __syncthreads();
  a_mul(0, b_iah, IMG0H, IMG0L, false);       __syncthreads();
  he_gemm(128, b_eout);                       __syncthreads();
  a_mul(1, b_oah, IMG1H, IMG1L, true);        __syncthreads();

  const int nl = wid*16 + l15;
  const char* APH[3] = {IMG0H, IMG1H, HH};
  const char* APL[3] = {IMG0L, IMG1L, HL};

  // ---- P4 sweep 1: gates r,i (acc = 8 f32x4) ----
  float rg_[4][4], ig_[4][4];
  {
    f32x4 aRI[4][2];
#pragma unroll
    for (int i = 0; i < 4; ++i) { aRI[i][0] = (f32x4){0,0,0,0}; aRI[i][1] = (f32x4){0,0,0,0}; }
#pragma unroll
    for (int kh = 0; kh < 3; ++kh) {
      const char* AH = APH[kh];
      const char* AL = APL[kh];
      for (int s = 0; s < 4; ++s) {
#pragma unroll
        for (int g = 0; g < 2; ++g) {
          unsigned boff = (unsigned)((g*128 + nl)*768 + kh*256 + s*64 + lq*16);
          bf16x8 bh = *(const bf16x8*)(wsb + WS_WCATH + boff);
          bf16x8 bl = *(const bf16x8*)(wsb + WS_WCATL + boff);
#pragma unroll
          for (int i = 0; i < 4; ++i) {
            int row = i*16 + l15;
            unsigned off = row*256 + (((unsigned)(s*64 + lq*16)) ^ (((unsigned)(row&7)) << 4));
            bf16x8 ah = *(const bf16x8*)(AH + off);
            bf16x8 al = *(const bf16x8*)(AL + off);
            aRI[i][g] = __builtin_amdgcn_mfma_f32_16x16x32_bf16(ah, bh, aRI[i][g], 0,0,0);
            aRI[i][g] = __builtin_amdgcn_mfma_f32_16x16x32_bf16(ah, bl, aRI[i][g], 0,0,0);
            aRI[i][g] = __builtin_amdgcn_mfma_f32_16x16x32_bf16(al, bh, aRI[i][g], 0,0,0);
          }
        }
      }
    }
    float bir = b_ih[nl], bii = b_ih[128+nl];
    float bhr = b_hh[nl], bhi = b_hh[128+nl];
#pragma unroll
    for (int i = 0; i < 4; ++i)
#pragma unroll
      for (int q = 0; q < 4; ++q) {
        rg_[i][q] = sigm(aRI[i][0][q] + bir + bhr);
        ig_[i][q] = sigm(aRI[i][1][q] + bii + bhi);
      }
  }

  // ---- P4 sweep 2: gate n (Ni from kh0/1, Nh from kh2) ----
  {
    f32x4 aN[4], hN[4];
#pragma unroll
    for (int i = 0; i < 4; ++i) { aN[i] = (f32x4){0,0,0,0}; hN[i] = (f32x4){0,0,0,0}; }
#pragma unroll
    for (int kh = 0; kh < 3; ++kh) {
      const char* AH = APH[kh];
      const char* AL = APL[kh];
      for (int s = 0; s < 4; ++s) {
        unsigned boff = (unsigned)((256 + nl)*768 + kh*256 + s*64 + lq*16);
        bf16x8 bh = *(const bf16x8*)(wsb + WS_WCATH + boff);
        bf16x8 bl = *(const bf16x8*)(wsb + WS_WCATL + boff);
#pragma unroll
        for (int i = 0; i < 4; ++i) {
          int row = i*16 + l15;
          unsigned off = row*256 + (((unsigned)(s*64 + lq*16)) ^ (((unsigned)(row&7)) << 4));
          bf16x8 ah = *(const bf16x8*)(AH + off);
          bf16x8 al = *(const bf16x8*)(AL + off);
          if (kh < 2) {
            aN[i] = __builtin_amdgcn_mfma_f32_16x16x32_bf16(ah, bh, aN[i], 0,0,0);
            aN[i] = __builtin_amdgcn_mfma_f32_16x16x32_bf16(ah, bl, aN[i], 0,0,0);
            aN[i] = __builtin_amdgcn_mfma_f32_16x16x32_bf16(al, bh, aN[i], 0,0,0);
          } else {
            hN[i] = __builtin_amdgcn_mfma_f32_16x16x32_bf16(ah, bh, hN[i], 0,0,0);
            hN[i] = __builtin_amdgcn_mfma_f32_16x16x32_bf16(ah, bl, hN[i], 0,0,0);
            hN[i] = __builtin_amdgcn_mfma_f32_16x16x32_bf16(al, bh, hN[i], 0,0,0);
          }
        }
      }
    }
    __syncthreads();   // IMG reads done before H2f overlays IMG0
    // ---- GRU pointwise epilogue -> H2f plain [50][128] ----
    float bin_ = b_ih[256+nl], bhn = b_hh[256+nl];
#pragma unroll
    for (int i = 0; i < 4; ++i) {
#pragma unroll
      for (int q = 0; q < 4; ++q) {
        int row = i*16 + lq*4 + q;
        if (row < 50) {
          float ng_ = tanhf(aN[i][q] + bin_ + rg_[i][q]*(hN[i][q] + bhn));
          unsigned byte = row*256 + (((unsigned)(nl*2)) ^ (((unsigned)(row&7)) << 4));
          float h = bf2f(*(const unsigned short*)(HH + byte))
                  + bf2f(*(const unsigned short*)(HL + byte));
          H2f[row*128 + nl] = ng_ + ig_[i][q]*(h - ng_);
        }
      }
    }
  }
  __syncthreads();   // HH reads done -> small buffers may overlay

  if (tid < LLn) ALI[tid] = alias_in[b*LLn + tid];
  __syncthreads();

  // ---- P5: attention readout (plain layouts; vector reads are row-broadcasts) ----
  int cnt = 0;
  for (int l = 0; l < LLn; ++l) cnt += (ALI[l] > 0) ? 1 : 0;
  int last = cnt - 1; if (last < 0) last = LLn - 1;
  const int a_last = ALI[last];

  const int c = tid & 127, h4 = tid >> 7;
  const float* W1T = (const float*)(wsb + WS_W1T);
  const float* W2T = (const float*)(wsb + WS_W2T);
  const float* WtT = (const float*)(wsb + WS_WTT);

  { // q1 partial over k-quarter
    float q = 0.f;
    for (int k = h4*32; k < h4*32 + 32; k += 4) {
      float4 x = *(const float4*)&H2f[a_last*128 + k];
      q += x.x*W1T[(k<<7)+c] + x.y*W1T[((k+1)<<7)+c]
         + x.z*W1T[((k+2)<<7)+c] + x.w*W1T[((k+3)<<7)+c];
    }
    Q1P[h4*128 + c] = q;
  }
  __syncthreads();

  { // q2 + sigmoid, rows l = h4 + 4*ii
    int al_[13];
#pragma unroll
    for (int ii = 0; ii < 13; ++ii) {
      int l = h4 + 4*ii;
      al_[ii] = (l < LLn) ? ALI[l] : 0;
    }
    float q2a[13];
#pragma unroll
    for (int ii = 0; ii < 13; ++ii) q2a[ii] = 0.f;
    for (int k = 0; k < HD; k += 4) {
      float w0 = W2T[(k<<7)+c],     w1 = W2T[((k+1)<<7)+c];
      float w2 = W2T[((k+2)<<7)+c], w3 = W2T[((k+3)<<7)+c];
#pragma unroll
      for (int ii = 0; ii < 13; ++ii) {
        float4 x = *(const float4*)&H2f[al_[ii]*128 + k];
        q2a[ii] += x.x*w0 + x.y*w1 + x.z*w2 + x.w*w3;
      }
    }
    float q1c = Q1P[c] + Q1P[128+c] + Q1P[256+c] + Q1P[384+c] + b1[c] + b2[c];
#pragma unroll
    for (int ii = 0; ii < 13; ++ii) {
      int l = h4 + 4*ii;
      if (l < LLn) SIG[l*128 + c] = sigm(q1c + q2a[ii]);
    }
  }
  __syncthreads();

  if (tid < 400) { // alpha = sig @ W3, 8 threads/row
    int l = tid >> 3, qd = tid & 7;
    float sum = 0.f;
    for (int cc = qd*16; cc < qd*16 + 16; cc += 4) {
      float4 x = *(const float4*)&SIG[l*128 + cc];
      sum += x.x*W3[cc] + x.y*W3[cc+1] + x.z*W3[cc+2] + x.w*W3[cc+3];
    }
    sum += __shfl_xor(sum, 1);
    sum += __shfl_xor(sum, 2);
    sum += __shfl_xor(sum, 4);
    if (qd == 0) ALP[l] = (ALI[l] > 0) ? sum : 0.f;
  }
  __syncthreads();

  { // a partial over l-quarter
    float acc = 0.f;
    int l0 = h4*13, l1 = l0 + 13; if (l1 > LLn) l1 = LLn;
    for (int l = l0; l < l1; ++l)
      acc += ALP[l] * H2f[ALI[l]*128 + c];
    AP[h4*128 + c] = acc;
  }
  __syncthreads();

  { // final r partial over k-quarter
    float r = 0.f;
    for (int k = h4*32; k < h4*32 + 32; ++k) {
      float av = AP[k] + AP[128+k] + AP[256+k] + AP[384+k];
      r += av * WtT[(k<<7) + c] + H2f[a_last*128 + k] * WtT[((128+k)<<7) + c];
    }
    RP[h4*128 + c] = r;
  }
  __syncthreads();

  if (tid < 128) {
    float r = bt_[c] + RP[c] + RP[128+c] + RP[256+c] + RP[384+c];
    int kh = c >> 6, kl = c & 63;
    unsigned int cb = (unsigned int)(kl*2) ^ (((unsigned int)(b & 7)) << 4);
    unsigned short hi = f2bf(r);
    unsigned short lo = f2bf(r - bf2f(hi));
    *(unsigned short*)(wsb + WS_AHI + kh*65536 + b*128 + cb) = hi;
    *(unsigned short*)(wsb + WS_ALO + kh*65536 + b*128 + cb) = lo;
  }
}

// ================= k2: scores GEMM (unchanged, proven) =================
__global__ __launch_bounds__(512) void k2_mfma(const float* __restrict__ emb,
                                               const char* __restrict__ wsb,
                                               float* __restrict__ out)
{
  extern __shared__ char ldsc[];
  char* AHI = ldsc;
  char* ALO = ldsc + 32768;
  char* EHI = ldsc + 65536;
  char* ELO = ldsc + 81920;

  const int tid  = threadIdx.x;
  const int lane = tid & 63;
  const int wid  = tid >> 6;
  const int wm   = wid >> 1;
  const int wn   = wid & 1;
  const int j0   = blockIdx.x * 128;
  const int l15  = lane & 15, lq = lane >> 4;

  f32x4 acc[2][4][4];
#pragma unroll
  for (int bi = 0; bi < 2; ++bi)
#pragma unroll
    for (int i = 0; i < 4; ++i)
#pragma unroll
      for (int j = 0; j < 4; ++j) acc[bi][i][j] = (f32x4){0.f, 0.f, 0.f, 0.f};

  for (int kh = 0; kh < 2; ++kh) {
    {
      int rbase = tid >> 4, c4 = tid & 15;
#pragma unroll
      for (int rr = 0; rr < 4; ++rr) {
        int row = rbase + rr*32;
        int j = j0 + row; if (j > OUTN - 1) j = OUTN - 1;
        float4 v = *(const float4*)&emb[(size_t)(1 + j)*HD + kh*64 + c4*4];
        ushort4 hi4, lo4;
        cvt4(v, hi4, lo4);
        unsigned int off = (unsigned int)(row*128) + (((unsigned int)(c4*8)) ^ (((unsigned int)(row&7)) << 4));
        *(ushort4*)(EHI + off) = hi4;
        *(ushort4*)(ELO + off) = lo4;
      }
    }
#pragma unroll
    for (int bi = 0; bi < 2; ++bi) {
      const char* srcH = wsb + WS_AHI + kh*65536 + bi*32768;
      const char* srcL = wsb + WS_ALO + kh*65536 + bi*32768;
#pragma unroll
      for (int r = 0; r < 4; ++r) {
        int off = (r*512 + tid) * 16;
        gl_lds16(srcH + off, AHI + off);
        gl_lds16(srcL + off, ALO + off);
      }
      __syncthreads();

#pragma unroll
      for (int s = 0; s < 2; ++s) {
        bf16x8 ah[4], al[4], bh[4], bl[4];
        const unsigned int cb = (unsigned int)(s*64 + (lq << 4));
#pragma unroll
        for (int i = 0; i < 4; ++i) {
          int row = wm*64 + i*16 + l15;
          unsigned int off = (unsigned int)(row*128) + (cb ^ (((unsigned int)(row&7)) << 4));
          ah[i] = *(const bf16x8*)(AHI + off);
          al[i] = *(const bf16x8*)(ALO + off);
        }
#pragma unroll
        for (int j = 0; j < 4; ++j) {
          int row = wn*64 + j*16 + l15;
          unsigned int off = (unsigned int)(row*128) + (cb ^ (((unsigned int)(row&7)) << 4));
          bh[j] = *(const bf16x8*)(EHI + off);
          bl[j] = *(const bf16x8*)(ELO + off);
        }
#pragma unroll
        for (int i = 0; i < 4; ++i)
#pragma unroll
          for (int j = 0; j < 4; ++j) {
            acc[bi][i][j] = __builtin_amdgcn_mfma_f32_16x16x32_bf16(ah[i], bh[j], acc[bi][i][j], 0, 0, 0);
            acc[bi][i][j] = __builtin_amdgcn_mfma_f32_16x16x32_bf16(ah[i], bl[j], acc[bi][i][j], 0, 0, 0);
            acc[bi][i][j] = __builtin_amdgcn_mfma_f32_16x16x32_bf16(al[i], bh[j], acc[bi][i][j], 0, 0, 0);
          }
      }
      __syncthreads();
    }
  }

#pragma unroll
  for (int bi = 0; bi < 2; ++bi)
#pragma unroll
    for (int i = 0; i < 4; ++i) {
#pragma unroll
      for (int j = 0; j < 4; ++j) {
        int jj = j0 + wn*64 + j*16 + l15;
        if (jj < OUTN) {
          size_t rowbase = (size_t)(bi*256 + wm*64 + i*16 + lq*4);
#pragma unroll
          for (int q = 0; q < 4; ++q)
            out[(rowbase + q)*OUTN + jj] = acc[bi][i][j][q];
        }
      }
    }
}

extern "C" void kernel_launch(void* const* d_in, const int* in_sizes, int n_in,
                              void* d_out, int out_size, void* d_ws, size_t ws_size,
                              hipStream_t stream)
{
  const int*   items  = (const int*)  d_in[0];
  const float* A      = (const float*)d_in[1];
  const int*   alias  = (const int*)  d_in[2];
  const float* emb    = (const float*)d_in[3];
  const float* w_ih   = (const float*)d_in[4];
  const float* w_hh   = (const float*)d_in[5];
  const float* b_ih   = (const float*)d_in[6];
  const float* b_hh   = (const float*)d_in[7];
  const float* b_iah  = (const float*)d_in[8];
  const float* b_oah  = (const float*)d_in[9];
  const float* W_ein  = (const float*)d_in[10];
  const float* b_ein  = (const float*)d_in[11];
  const float* W_eout = (const float*)d_in[12];
  const float* b_eout = (const float*)d_in[13];
  const float* W1     = (const float*)d_in[14];
  const float* b1     = (const float*)d_in[15];
  const float* W2     = (const float*)d_in[16];
  const float* b2     = (const float*)d_in[17];
  const float* W3     = (const float*)d_in[18];
  const float* Wt     = (const float*)d_in[19];
  const float* bt_    = (const float*)d_in[20];

  char*  wsb  = (char*)d_ws;
  float* outf = (float*)d_out;

  k0_prep<<<240, 256, 0, stream>>>(w_ih, w_hh, W_ein, W_eout, W1, W2, Wt, wsb);

  k1f<<<NB, 512, 81920, stream>>>(items, A, emb, alias, b_ein, b_eout, b_iah, b_oah,
                                  b_ih, b_hh, b1, b2, W3, bt_, wsb);

  k2_mfma<<<dim3(782, 1), 512, 98304, stream>>>(emb, (const char*)d_ws, outf);
}

// Round 11
// 181.018 us; speedup vs baseline: 4.5351x; 4.5351x over previous
//
#include <hip/hip_runtime.h>

#define NB   512
#define NN   50
#define LLn  50
#define HD   128
#define OUTN 99999

// ---------------- ws byte offsets ----------------
#define WS_W1T   0         // fp32 [128][128] transposed
#define WS_W2T   65536     // fp32 [128][128] transposed (unused now, kept)
#define WS_WTT   131072    // fp32 [256][128] transposed
#define WS_WEH   262144    // bf16 hi [256 n][128 k]
#define WS_WEL   327680
#define WS_WCATH 393216    // bf16 hi [384 n][384 k]
#define WS_WCATL 688128
#define WS_AHI   983040    // a-final hi image [2 kh][512 b][128 B]
#define WS_ALO   1114112
#define WS_W2H   1245184   // bf16 hi [128 n][128 k]
#define WS_W2L   1277952

// ---------------- k1f LDS (131072 B, 1 blk/CU) ----------------
// 0      AI0H 8K | AI0L 8K | AI1H 8K | AI1L 8K   (A adjacency images [64n][64m])
//        -> after a_mul: IMG0H 16K @0, IMG0L 16K @16384
//        -> in P5: SIG [50][128]f @0
// 32768  HH [64][256B] hi | 49152 HL lo          (hidden images; rows>=50 zero)
//        -> P5 small: Q1P@32768 AP@34816 RP@36864 ALP@38912 ALI@39168
// 65536  HETH [256c][128B] | 98304 HETL          (he transposed images, m-pad zero)
//        -> after a_mul: IMG1H@65536 16K, IMG1L@81920 16K
//        -> after cat:   H2H@65536 16K, H2L@81920 16K, H2f@98304 [50][128]f

typedef __attribute__((ext_vector_type(8))) short bf16x8;
typedef __attribute__((ext_vector_type(4))) float f32x4;

__device__ __forceinline__ unsigned short f2bf(float f) {
  unsigned int u = __float_as_uint(f);
  unsigned int r = (u + 0x7FFFu + ((u >> 16) & 1u)) >> 16;
  return (unsigned short)r;
}
__device__ __forceinline__ float bf2f(unsigned short h) {
  return __uint_as_float(((unsigned int)h) << 16);
}
__device__ __forceinline__ void cvt4(float4 v, ushort4& hi, ushort4& lo) {
  unsigned short h0 = f2bf(v.x), h1 = f2bf(v.y), h2 = f2bf(v.z), h3 = f2bf(v.w);
  hi = make_ushort4(h0, h1, h2, h3);
  lo = make_ushort4(f2bf(v.x - bf2f(h0)), f2bf(v.y - bf2f(h1)),
                    f2bf(v.z - bf2f(h2)), f2bf(v.w - bf2f(h3)));
}
__device__ __forceinline__ void gl_lds16(const void* g, void* l) {
  __builtin_amdgcn_global_load_lds(
      (const __attribute__((address_space(1))) void*)g,
      (__attribute__((address_space(3))) void*)l, 16, 0, 0);
}
__device__ __forceinline__ float sigm(float x) { return 1.f/(1.f + __expf(-x)); }

// ================= k0: weight prep (+W2 bf16 images) =================
__global__ void k0_prep(const float* __restrict__ w_ih, const float* __restrict__ w_hh,
                        const float* __restrict__ W_ein, const float* __restrict__ W_eout,
                        const float* __restrict__ W1, const float* __restrict__ W2,
                        const float* __restrict__ Wt, char* __restrict__ wsb)
{
  float* wsf = (float*)wsb;
  for (int i = blockIdx.x * blockDim.x + threadIdx.x; i < 262144; i += gridDim.x * blockDim.x) {
    int idx = i;
    if (idx < 16384) { int k = idx >> 7, c = idx & 127; wsf[idx] = W1[c*128 + k]; continue; }
    idx -= 16384;
    if (idx < 16384) { int k = idx >> 7, c = idx & 127; wsf[16384 + idx] = W2[c*128 + k]; continue; }
    idx -= 16384;
    if (idx < 32768) { int k = idx >> 7, c = idx & 127; wsf[32768 + idx] = Wt[c*256 + k]; continue; }
    idx -= 32768;
    if (idx < 32768) {
      int n = idx >> 7, k = idx & 127;
      float v = (n < 128) ? W_ein[n*128 + k] : W_eout[(n-128)*128 + k];
      unsigned short h = f2bf(v);
      *(unsigned short*)(wsb + WS_WEH + idx*2) = h;
      *(unsigned short*)(wsb + WS_WEL + idx*2) = f2bf(v - bf2f(h));
      continue;
    }
    idx -= 32768;
    if (idx < 147456) {
      int n = idx / 384, k = idx % 384;
      float v = (k < 256) ? w_ih[n*256 + k] : w_hh[n*128 + (k - 256)];
      unsigned short h = f2bf(v);
      *(unsigned short*)(wsb + WS_WCATH + idx*2) = h;
      *(unsigned short*)(wsb + WS_WCATL + idx*2) = f2bf(v - bf2f(h));
      continue;
    }
    idx -= 147456;
    {
      float v = W2[idx];   // [128 n][128 k] linear
      unsigned short h = f2bf(v);
      *(unsigned short*)(wsb + WS_W2H + idx*2) = h;
      *(unsigned short*)(wsb + WS_W2L + idx*2) = f2bf(v - bf2f(h));
    }
  }
}

// ================= k1f: fused per-sample GNN+GRU+attention (MFMA-heavy) =========
__global__ __launch_bounds__(512) void k1f(const int* __restrict__ items,
    const float* __restrict__ A, const float* __restrict__ emb,
    const int* __restrict__ alias_in,
    const float* __restrict__ b_ein, const float* __restrict__ b_eout,
    const float* __restrict__ b_iah, const float* __restrict__ b_oah,
    const float* __restrict__ b_ih, const float* __restrict__ b_hh,
    const float* __restrict__ b1, const float* __restrict__ b2,
    const float* __restrict__ W3, const float* __restrict__ bt_,
    char* __restrict__ wsb)
{
  extern __shared__ char lds[];
  char*  IMG0H = lds;
  char*  IMG0L = lds + 16384;
  float* SIG   = (float*)lds;
  char*  HH    = lds + 32768;
  char*  HL    = lds + 49152;
  char*  HETH  = lds + 65536;
  char*  HETL  = lds + 98304;
  char*  IMG1H = lds + 65536;
  char*  IMG1L = lds + 81920;
  char*  H2H   = lds + 65536;
  char*  H2L   = lds + 81920;
  float* H2f   = (float*)(lds + 98304);
  float* Q1P   = (float*)(lds + 32768);
  float* AP    = (float*)(lds + 34816);
  float* RP    = (float*)(lds + 36864);
  float* ALP   = (float*)(lds + 38912);
  int*   ALI   = (int*)(lds + 39168);

  const int b = blockIdx.x, tid = threadIdx.x;
  const int lane = tid & 63, wid = tid >> 6, l15 = lane & 15, lq = lane >> 4;

  // ---- P1: zero he_t pads; build A images; gather emb -> HH/HL ----
  for (int i = tid; i < 7168; i += 512) {
    int bufsel = (i >= 3584), e = bufsel ? i - 3584 : i;
    int cc = e / 14, m = 50 + e % 14;
    unsigned adr = (unsigned)(cc*128) + (((unsigned)(m*2)) ^ (((unsigned)(cc&7)) << 4));
    *(unsigned short*)((bufsel ? HETL : HETH) + adr) = 0;
  }
  {
    const float* Ab = A + (size_t)b*NN*100;
    for (int i = tid; i < 8192; i += 512) {
      int sel = i >> 12, e = i & 4095, n = e >> 6, m = e & 63;
      float v = (n < 50 && m < 50) ? Ab[n*100 + sel*50 + m] : 0.f;
      unsigned short hi = f2bf(v);
      unsigned short lo = f2bf(v - bf2f(hi));
      unsigned adr = (unsigned)(n*128) + (((unsigned)(m*2)) ^ (((unsigned)(n&7)) << 4));
      *(unsigned short*)(lds + sel*16384 + adr) = hi;
      *(unsigned short*)(lds + sel*16384 + 8192 + adr) = lo;
    }
  }
  for (int i = tid; i < 2048; i += 512) {
    int row = i >> 5, part = i & 31;
    float4 v = make_float4(0.f,0.f,0.f,0.f);
    if (row < 50) {
      int it = items[b*NN + row];
      v = *(const float4*)&emb[(size_t)it*128 + part*4];
    }
    ushort4 h4v, g4v;
    cvt4(v, h4v, g4v);
    unsigned off = row*256 + (((unsigned)(part*8)) ^ (((unsigned)(row&7)) << 4));
    *(ushort4*)(HH + off) = h4v;
    *(ushort4*)(HL + off) = g4v;
  }
  __syncthreads();

  // ---- P2: he GEMM (M=64 m, N=256 c, K=128) -> transposed he_t images ----
  {
    f32x4 acc2[4][2];
#pragma unroll
    for (int i = 0; i < 4; ++i) { acc2[i][0] = (f32x4){0,0,0,0}; acc2[i][1] = (f32x4){0,0,0,0}; }
    for (int s = 0; s < 4; ++s) {
      bf16x8 ah[4], al[4];
#pragma unroll
      for (int i = 0; i < 4; ++i) {
        int row = i*16 + l15;
        unsigned off = row*256 + (((unsigned)(s*64 + lq*16)) ^ (((unsigned)(row&7)) << 4));
        ah[i] = *(const bf16x8*)(HH + off);
        al[i] = *(const bf16x8*)(HL + off);
      }
#pragma unroll
      for (int j = 0; j < 2; ++j) {
        int nc = wid*32 + j*16 + l15;
        unsigned boff = (unsigned)(nc*256 + s*64 + lq*16);
        bf16x8 bh = *(const bf16x8*)(wsb + WS_WEH + boff);
        bf16x8 bl = *(const bf16x8*)(wsb + WS_WEL + boff);
#pragma unroll
        for (int i = 0; i < 4; ++i) {
          acc2[i][j] = __builtin_amdgcn_mfma_f32_16x16x32_bf16(ah[i], bh, acc2[i][j], 0,0,0);
          acc2[i][j] = __builtin_amdgcn_mfma_f32_16x16x32_bf16(ah[i], bl, acc2[i][j], 0,0,0);
          acc2[i][j] = __builtin_amdgcn_mfma_f32_16x16x32_bf16(al[i], bh, acc2[i][j], 0,0,0);
        }
      }
    }
#pragma unroll
    for (int j = 0; j < 2; ++j) {
      int nc = wid*32 + j*16 + l15;
      float bv = (nc < 128) ? b_ein[nc] : b_eout[nc - 128];
#pragma unroll
      for (int i = 0; i < 4; ++i)
#pragma unroll
        for (int q = 0; q < 4; ++q) {
          int m = i*16 + lq*4 + q;
          if (m < 50) {
            float v = acc2[i][j][q] + bv;
            unsigned short hi = f2bf(v);
            unsigned short lo = f2bf(v - bf2f(hi));
            unsigned adr = (unsigned)(nc*128) + (((unsigned)(m*2)) ^ (((unsigned)(nc&7)) << 4));
            *(unsigned short*)(HETH + adr) = hi;
            *(unsigned short*)(HETL + adr) = lo;
          }
        }
    }
  }
  __syncthreads();

  // ---- P3: IN = A @ he via MFMA (M=64 n, N=128 c per sel, K=64 m) ----
  {
    const int c = wid*16 + l15;
    f32x4 accS[2][4];
#pragma unroll
    for (int sel = 0; sel < 2; ++sel)
#pragma unroll
      for (int i = 0; i < 4; ++i) accS[sel][i] = (f32x4){0,0,0,0};
#pragma unroll
    for (int sel = 0; sel < 2; ++sel) {
#pragma unroll
      for (int s2 = 0; s2 < 2; ++s2) {
        int ct = sel*128 + c;
        unsigned badr = (unsigned)(ct*128) + (((unsigned)(s2*64 + lq*16)) ^ (((unsigned)(ct&7)) << 4));
        bf16x8 bh = *(const bf16x8*)(HETH + badr);
        bf16x8 bl = *(const bf16x8*)(HETL + badr);
#pragma unroll
        for (int i = 0; i < 4; ++i) {
          int n = i*16 + l15;
          unsigned aadr = (unsigned)(n*128) + (((unsigned)(s2*64 + lq*16)) ^ (((unsigned)(n&7)) << 4));
          bf16x8 ah = *(const bf16x8*)(lds + sel*16384 + aadr);
          bf16x8 al = *(const bf16x8*)(lds + sel*16384 + 8192 + aadr);
          accS[sel][i] = __builtin_amdgcn_mfma_f32_16x16x32_bf16(ah, bh, accS[sel][i], 0,0,0);
          accS[sel][i] = __builtin_amdgcn_mfma_f32_16x16x32_bf16(ah, bl, accS[sel][i], 0,0,0);
          accS[sel][i] = __builtin_amdgcn_mfma_f32_16x16x32_bf16(al, bh, accS[sel][i], 0,0,0);
        }
      }
    }
    __syncthreads();   // AI & he_t reads done; safe to overwrite with IMG0/IMG1
#pragma unroll
    for (int sel = 0; sel < 2; ++sel) {
      float bv = sel ? b_oah[c] : b_iah[c];
      char* dH = sel ? IMG1H : IMG0H;
      char* dL = sel ? IMG1L : IMG0L;
#pragma unroll
      for (int i = 0; i < 4; ++i)
#pragma unroll
        for (int q = 0; q < 4; ++q) {
          int row = i*16 + lq*4 + q;
          float v = accS[sel][i][q] + bv;
          unsigned short hi = f2bf(v);
          unsigned short lo = f2bf(v - bf2f(hi));
          unsigned adr = row*256 + (((unsigned)(c*2)) ^ (((unsigned)(row&7)) << 4));
          *(unsigned short*)(dH + adr) = hi;
          *(unsigned short*)(dL + adr) = lo;
        }
    }
  }
  __syncthreads();

  // ---- P4: cat-GEMM [IN0|IN1|H] @ [w_ih|w_hh]^T + GRU epilogue ----
  f32x4 accRI[4][2], accNi[4], accNh[4];
#pragma unroll
  for (int i = 0; i < 4; ++i) {
    accRI[i][0] = (f32x4){0,0,0,0}; accRI[i][1] = (f32x4){0,0,0,0};
    accNi[i] = (f32x4){0,0,0,0};    accNh[i] = (f32x4){0,0,0,0};
  }
  const int nl = wid*16 + l15;

  auto cat_gemm = [&](const char* AH, const char* AL, int kh, bool toNh) {
    for (int s = 0; s < 4; ++s) {
      bf16x8 ah[4], al[4];
#pragma unroll
      for (int i = 0; i < 4; ++i) {
        int row = i*16 + l15;
        unsigned off = row*256 + (((unsigned)(s*64 + lq*16)) ^ (((unsigned)(row&7)) << 4));
        ah[i] = *(const bf16x8*)(AH + off);
        al[i] = *(const bf16x8*)(AL + off);
      }
#pragma unroll
      for (int g = 0; g < 2; ++g) {
        unsigned boff = (unsigned)((g*128 + nl)*768 + kh*256 + s*64 + lq*16);
        bf16x8 bh = *(const bf16x8*)(wsb + WS_WCATH + boff);
        bf16x8 bl = *(const bf16x8*)(wsb + WS_WCATL + boff);
#pragma unroll
        for (int i = 0; i < 4; ++i) {
          accRI[i][g] = __builtin_amdgcn_mfma_f32_16x16x32_bf16(ah[i], bh, accRI[i][g], 0,0,0);
          accRI[i][g] = __builtin_amdgcn_mfma_f32_16x16x32_bf16(ah[i], bl, accRI[i][g], 0,0,0);
          accRI[i][g] = __builtin_amdgcn_mfma_f32_16x16x32_bf16(al[i], bh, accRI[i][g], 0,0,0);
        }
      }
      {
        unsigned boff = (unsigned)((256 + nl)*768 + kh*256 + s*64 + lq*16);
        bf16x8 bh = *(const bf16x8*)(wsb + WS_WCATH + boff);
        bf16x8 bl = *(const bf16x8*)(wsb + WS_WCATL + boff);
        if (toNh) {
#pragma unroll
          for (int i = 0; i < 4; ++i) {
            accNh[i] = __builtin_amdgcn_mfma_f32_16x16x32_bf16(ah[i], bh, accNh[i], 0,0,0);
            accNh[i] = __builtin_amdgcn_mfma_f32_16x16x32_bf16(ah[i], bl, accNh[i], 0,0,0);
            accNh[i] = __builtin_amdgcn_mfma_f32_16x16x32_bf16(al[i], bh, accNh[i], 0,0,0);
          }
        } else {
#pragma unroll
          for (int i = 0; i < 4; ++i) {
            accNi[i] = __builtin_amdgcn_mfma_f32_16x16x32_bf16(ah[i], bh, accNi[i], 0,0,0);
            accNi[i] = __builtin_amdgcn_mfma_f32_16x16x32_bf16(ah[i], bl, accNi[i], 0,0,0);
            accNi[i] = __builtin_amdgcn_mfma_f32_16x16x32_bf16(al[i], bh, accNi[i], 0,0,0);
          }
        }
      }
    }
  };

  cat_gemm(IMG0H, IMG0L, 0, false);
  cat_gemm(IMG1H, IMG1L, 1, false);
  cat_gemm(HH,    HL,    2, true);
  __syncthreads();   // IMG1 reads done before H2 images overlay

  // ---- GRU pointwise epilogue -> H2f plain + H2 bf16 images ----
  {
    const int c = nl;
    float bir = b_ih[c], bii = b_ih[128+c], bin_ = b_ih[256+c];
    float bhr = b_hh[c], bhi = b_hh[128+c], bhn  = b_hh[256+c];
#pragma unroll
    for (int i = 0; i < 4; ++i) {
#pragma unroll
      for (int q = 0; q < 4; ++q) {
        int row = i*16 + lq*4 + q;
        if (row < 50) {
          float rg = sigm(accRI[i][0][q] + bir + bhr);
          float ig = sigm(accRI[i][1][q] + bii + bhi);
          float ng_ = tanhf(accNi[i][q] + bin_ + rg*(accNh[i][q] + bhn));
          unsigned byte = row*256 + (((unsigned)(c*2)) ^ (((unsigned)(row&7)) << 4));
          float h = bf2f(*(const unsigned short*)(HH + byte))
                  + bf2f(*(const unsigned short*)(HL + byte));
          float hn = ng_ + ig*(h - ng_);
          H2f[row*128 + c] = hn;
          unsigned short hi = f2bf(hn);
          unsigned short lo = f2bf(hn - bf2f(hi));
          *(unsigned short*)(H2H + byte) = hi;
          *(unsigned short*)(H2L + byte) = lo;
        }
      }
    }
  }
  __syncthreads();   // HH reads done -> small buffers may overlay

  if (tid < 64) ALI[tid] = (tid < LLn) ? alias_in[b*LLn + tid] : 0;
  __syncthreads();

  // ---- P5: attention readout ----
  int cnt = 0;
  for (int l = 0; l < LLn; ++l) cnt += (ALI[l] > 0) ? 1 : 0;
  int last = cnt - 1; if (last < 0) last = LLn - 1;
  const int a_last = ALI[last];

  const int c = tid & 127, h4 = tid >> 7;
  const float* W1T = (const float*)(wsb + WS_W1T);
  const float* WtT = (const float*)(wsb + WS_WTT);

  { // q1 partial over k-quarter (VALU, small)
    float q = 0.f;
    for (int k = h4*32; k < h4*32 + 32; k += 4) {
      float4 x = *(const float4*)&H2f[a_last*128 + k];
      q += x.x*W1T[(k<<7)+c] + x.y*W1T[((k+1)<<7)+c]
         + x.z*W1T[((k+2)<<7)+c] + x.w*W1T[((k+3)<<7)+c];
    }
    Q1P[h4*128 + c] = q;
  }
  __syncthreads();

  { // q2 via MFMA: rows l (gather alias), cols c, K=128
    const int cq = nl;
    f32x4 qa[4];
#pragma unroll
    for (int i = 0; i < 4; ++i) qa[i] = (f32x4){0,0,0,0};
    for (int s = 0; s < 4; ++s) {
      unsigned boff = (unsigned)(cq*256 + s*64 + lq*16);
      bf16x8 bh = *(const bf16x8*)(wsb + WS_W2H + boff);
      bf16x8 bl = *(const bf16x8*)(wsb + WS_W2L + boff);
#pragma unroll
      for (int i = 0; i < 4; ++i) {
        int ali = ALI[i*16 + l15];
        unsigned aadr = ali*256 + (((unsigned)(s*64 + lq*16)) ^ (((unsigned)(ali&7)) << 4));
        bf16x8 ah = *(const bf16x8*)(H2H + aadr);
        bf16x8 al = *(const bf16x8*)(H2L + aadr);
        qa[i] = __builtin_amdgcn_mfma_f32_16x16x32_bf16(ah, bh, qa[i], 0,0,0);
        qa[i] = __builtin_amdgcn_mfma_f32_16x16x32_bf16(ah, bl, qa[i], 0,0,0);
        qa[i] = __builtin_amdgcn_mfma_f32_16x16x32_bf16(al, bh, qa[i], 0,0,0);
      }
    }
    float q1c = Q1P[cq] + Q1P[128+cq] + Q1P[256+cq] + Q1P[384+cq] + b1[cq] + b2[cq];
#pragma unroll
    for (int i = 0; i < 4; ++i)
#pragma unroll
      for (int q = 0; q < 4; ++q) {
        int l = i*16 + lq*4 + q;
        if (l < 50) SIG[l*128 + cq] = sigm(q1c + qa[i][q]);
      }
  }
  __syncthreads();

  if (tid < 400) { // alpha = sig @ W3, 8 threads/row
    int l = tid >> 3, qd = tid & 7;
    float sum = 0.f;
    for (int cc = qd*16; cc < qd*16 + 16; cc += 4) {
      float4 x = *(const float4*)&SIG[l*128 + cc];
      sum += x.x*W3[cc] + x.y*W3[cc+1] + x.z*W3[cc+2] + x.w*W3[cc+3];
    }
    sum += __shfl_xor(sum, 1);
    sum += __shfl_xor(sum, 2);
    sum += __shfl_xor(sum, 4);
    if (qd == 0) ALP[l] = (ALI[l] > 0) ? sum : 0.f;
  }
  __syncthreads();

  { // a partial over l-quarter
    float acc = 0.f;
    int l0 = h4*13, l1 = l0 + 13; if (l1 > LLn) l1 = LLn;
    for (int l = l0; l < l1; ++l)
      acc += ALP[l] * H2f[ALI[l]*128 + c];
    AP[h4*128 + c] = acc;
  }
  __syncthreads();

  { // final r partial over k-quarter
    float r = 0.f;
    for (int k = h4*32; k < h4*32 + 32; ++k) {
      float av = AP[k] + AP[128+k] + AP[256+k] + AP[384+k];
      r += av * WtT[(k<<7) + c] + H2f[a_last*128 + k] * WtT[((128+k)<<7) + c];
    }
    RP[h4*128 + c] = r;
  }
  __syncthreads();

  if (tid < 128) {
    float r = bt_[c] + RP[c] + RP[128+c] + RP[256+c] + RP[384+c];
    int kh = c >> 6, kl = c & 63;
    unsigned int cb = (unsigned int)(kl*2) ^ (((unsigned int)(b & 7)) << 4);
    unsigned short hi = f2bf(r);
    unsigned short lo = f2bf(r - bf2f(hi));
    *(unsigned short*)(wsb + WS_AHI + kh*65536 + b*128 + cb) = hi;
    *(unsigned short*)(wsb + WS_ALO + kh*65536 + b*128 + cb) = lo;
  }
}

// ================= k2: scores GEMM (unchanged, proven) =================
__global__ __launch_bounds__(512) void k2_mfma(const float* __restrict__ emb,
                                               const char* __restrict__ wsb,
                                               float* __restrict__ out)
{
  extern __shared__ char ldsc[];
  char* AHI = ldsc;
  char* ALO = ldsc + 32768;
  char* EHI = ldsc + 65536;
  char* ELO = ldsc + 81920;

  const int tid  = threadIdx.x;
  const int lane = tid & 63;
  const int wid  = tid >> 6;
  const int wm   = wid >> 1;
  const int wn   = wid & 1;
  const int j0   = blockIdx.x * 128;
  const int l15  = lane & 15, lq = lane >> 4;

  f32x4 acc[2][4][4];
#pragma unroll
  for (int bi = 0; bi < 2; ++bi)
#pragma unroll
    for (int i = 0; i < 4; ++i)
#pragma unroll
      for (int j = 0; j < 4; ++j) acc[bi][i][j] = (f32x4){0.f, 0.f, 0.f, 0.f};

  for (int kh = 0; kh < 2; ++kh) {
    {
      int rbase = tid >> 4, c4 = tid & 15;
#pragma unroll
      for (int rr = 0; rr < 4; ++rr) {
        int row = rbase + rr*32;
        int j = j0 + row; if (j > OUTN - 1) j = OUTN - 1;
        float4 v = *(const float4*)&emb[(size_t)(1 + j)*HD + kh*64 + c4*4];
        ushort4 hi4, lo4;
        cvt4(v, hi4, lo4);
        unsigned int off = (unsigned int)(row*128) + (((unsigned int)(c4*8)) ^ (((unsigned int)(row&7)) << 4));
        *(ushort4*)(EHI + off) = hi4;
        *(ushort4*)(ELO + off) = lo4;
      }
    }
#pragma unroll
    for (int bi = 0; bi < 2; ++bi) {
      const char* srcH = wsb + WS_AHI + kh*65536 + bi*32768;
      const char* srcL = wsb + WS_ALO + kh*65536 + bi*32768;
#pragma unroll
      for (int r = 0; r < 4; ++r) {
        int off = (r*512 + tid) * 16;
        gl_lds16(srcH + off, AHI + off);
        gl_lds16(srcL + off, ALO + off);
      }
      __syncthreads();

#pragma unroll
      for (int s = 0; s < 2; ++s) {
        bf16x8 ah[4], al[4], bh[4], bl[4];
        const unsigned int cb = (unsigned int)(s*64 + (lq << 4));
#pragma unroll
        for (int i = 0; i < 4; ++i) {
          int row = wm*64 + i*16 + l15;
          unsigned int off = (unsigned int)(row*128) + (cb ^ (((unsigned int)(row&7)) << 4));
          ah[i] = *(const bf16x8*)(AHI + off);
          al[i] = *(const bf16x8*)(ALO + off);
        }
#pragma unroll
        for (int j = 0; j < 4; ++j) {
          int row = wn*64 + j*16 + l15;
          unsigned int off = (unsigned int)(row*128) + (cb ^ (((unsigned int)(row&7)) << 4));
          bh[j] = *(const bf16x8*)(EHI + off);
          bl[j] = *(const bf16x8*)(ELO + off);
        }
#pragma unroll
        for (int i = 0; i < 4; ++i)
#pragma unroll
          for (int j = 0; j < 4; ++j) {
            acc[bi][i][j] = __builtin_amdgcn_mfma_f32_16x16x32_bf16(ah[i], bh[j], acc[bi][i][j], 0, 0, 0);
            acc[bi][i][j] = __builtin_amdgcn_mfma_f32_16x16x32_bf16(ah[i], bl[j], acc[bi][i][j], 0, 0, 0);
            acc[bi][i][j] = __builtin_amdgcn_mfma_f32_16x16x32_bf16(al[i], bh[j], acc[bi][i][j], 0, 0, 0);
          }
      }
      __syncthreads();
    }
  }

#pragma unroll
  for (int bi = 0; bi < 2; ++bi)
#pragma unroll
    for (int i = 0; i < 4; ++i) {
#pragma unroll
      for (int j = 0; j < 4; ++j) {
        int jj = j0 + wn*64 + j*16 + l15;
        if (jj < OUTN) {
          size_t rowbase = (size_t)(bi*256 + wm*64 + i*16 + lq*4);
#pragma unroll
          for (int q = 0; q < 4; ++q)
            out[(rowbase + q)*OUTN + jj] = acc[bi][i][j][q];
        }
      }
    }
}

extern "C" void kernel_launch(void* const* d_in, const int* in_sizes, int n_in,
                              void* d_out, int out_size, void* d_ws, size_t ws_size,
                              hipStream_t stream)
{
  const int*   items  = (const int*)  d_in[0];
  const float* A      = (const float*)d_in[1];
  const int*   alias  = (const int*)  d_in[2];
  const float* emb    = (const float*)d_in[3];
  const float* w_ih   = (const float*)d_in[4];
  const float* w_hh   = (const float*)d_in[5];
  const float* b_ih   = (const float*)d_in[6];
  const float* b_hh   = (const float*)d_in[7];
  const float* b_iah  = (const float*)d_in[8];
  const float* b_oah  = (const float*)d_in[9];
  const float* W_ein  = (const float*)d_in[10];
  const float* b_ein  = (const float*)d_in[11];
  const float* W_eout = (const float*)d_in[12];
  const float* b_eout = (const float*)d_in[13];
  const float* W1     = (const float*)d_in[14];
  const float* b1     = (const float*)d_in[15];
  const float* W2     = (const float*)d_in[16];
  const float* b2     = (const float*)d_in[17];
  const float* W3     = (const float*)d_in[18];
  const float* Wt     = (const float*)d_in[19];
  const float* bt_    = (const float*)d_in[20];

  char*  wsb  = (char*)d_ws;
  float* outf = (float*)d_out;

  k0_prep<<<240, 256, 0, stream>>>(w_ih, w_hh, W_ein, W_eout, W1, W2, Wt, wsb);

  k1f<<<NB, 512, 131072, stream>>>(items, A, emb, alias, b_ein, b_eout, b_iah, b_oah,
                                   b_ih, b_hh, b1, b2, W3, bt_, wsb);

  k2_mfma<<<dim3(782, 1), 512, 98304, stream>>>(emb, (const char*)d_ws, outf);
}